// Round 1
// baseline (320.537 us; speedup 1.0000x reference)
//
#include <hip/hip_runtime.h>

#define A_BATCH 128
#define M 512        // path length
#define D 16
#define MI 511       // inc dims (M-1)
#define P 512        // K-grid dim (MI+1)
#define NDIAG 1023   // MI + NI + 1
#define SY_STRIDE 17 // odd stride -> conflict-free LDS rows

__global__ __launch_bounds__(512, 4)
void sig_pde_kernel(const float* __restrict__ X, const float* __restrict__ Y,
                    float* __restrict__ out) {
    __shared__ float sy[MI * SY_STRIDE];   // dY rows, padded (~34 KB)
    __shared__ float kbuf[3][P + 1];       // rotating anti-diagonals (~6 KB)

    const int idx  = blockIdx.x;
    const int pair = idx >> 7;             // 0: XX, 1: YY, 2: XY
    const int a    = idx & 127;
    const float* Pp = (pair == 1) ? Y : X;
    const float* Qp = (pair == 0) ? X : Y;
    const float* prow = Pp + (size_t)a * M * D;
    const float* qrow = Qp + (size_t)a * M * D;

    const int i = threadIdx.x;

    // dX row (i-1) into registers: dX[r] = P[r+1]-P[r], r = i-1
    float xr[D];
    if (i >= 1) {
        const float4* r1 = (const float4*)(prow + (size_t)i * D);
        const float4* r0 = (const float4*)(prow + (size_t)(i - 1) * D);
        #pragma unroll
        for (int q = 0; q < 4; ++q) {
            float4 v1 = r1[q], v0 = r0[q];
            xr[4*q+0] = v1.x - v0.x;
            xr[4*q+1] = v1.y - v0.y;
            xr[4*q+2] = v1.z - v0.z;
            xr[4*q+3] = v1.w - v0.w;
        }
    } else {
        #pragma unroll
        for (int q = 0; q < D; ++q) xr[q] = 0.f;
    }

    // Stage dY rows into LDS (thread c loads row c)
    if (i < MI) {
        const float4* r1 = (const float4*)(qrow + (size_t)(i + 1) * D);
        const float4* r0 = (const float4*)(qrow + (size_t)i * D);
        #pragma unroll
        for (int q = 0; q < 4; ++q) {
            float4 v1 = r1[q], v0 = r0[q];
            sy[i * SY_STRIDE + 4*q + 0] = v1.x - v0.x;
            sy[i * SY_STRIDE + 4*q + 1] = v1.y - v0.y;
            sy[i * SY_STRIDE + 4*q + 2] = v1.z - v0.z;
            sy[i * SY_STRIDE + 4*q + 3] = v1.w - v0.w;
        }
    }
    kbuf[0][i] = 0.f; kbuf[1][i] = 0.f; kbuf[2][i] = 0.f;
    __syncthreads();

    // Wavefront over anti-diagonals.
    // diag d lives in kbuf[d%3]; prev = d-1, prev2 = d-2.
    float last = 0.f;
    float* b0 = kbuf[0];
    float* b1 = kbuf[1];   // will act as prev2 at d=0 (zeros)
    float* b2 = kbuf[2];   // will act as prev  at d=0 (zeros)
    for (int d = 0; d < NDIAG; ++d) {
        float* cur         = b0;
        const float* prev  = b2;
        const float* prev2 = b1;
        const int j = d - i;
        float v = 0.f;
        if (j >= 0 && j <= MI) {
            if (i == 0 || j == 0) {
                v = 1.f;
            } else {
                const float* yr = &sy[(j - 1) * SY_STRIDE];
                float dot = 0.f;
                #pragma unroll
                for (int q = 0; q < D; ++q) dot = fmaf(xr[q], yr[q], dot);
                v = prev[i] + prev[i - 1] + prev2[i - 1] * (dot - 1.0f);
            }
        }
        cur[i] = v;
        last = v;
        __syncthreads();
        // rotate: cur -> prev -> prev2 -> (reused as next cur)
        float* t = b1; b1 = b2; b2 = b0; b0 = t;
    }
    // Final cell (MI, MI) computed by thread MI at d = NDIAG-1
    if (i == MI) out[idx] = last;
}

__global__ void sig_reduce_kernel(const float* __restrict__ ws,
                                  float* __restrict__ out) {
    const int a = threadIdx.x;  // 128 threads
    float v = ws[a] + ws[128 + a] - 2.0f * ws[256 + a];
    #pragma unroll
    for (int off = 32; off >= 1; off >>= 1) v += __shfl_down(v, off, 64);
    __shared__ float partial[2];
    if ((a & 63) == 0) partial[a >> 6] = v;
    __syncthreads();
    if (a == 0) out[0] = (partial[0] + partial[1]) * (1.0f / 128.0f);
}

extern "C" void kernel_launch(void* const* d_in, const int* in_sizes, int n_in,
                              void* d_out, int out_size, void* d_ws, size_t ws_size,
                              hipStream_t stream) {
    const float* X = (const float*)d_in[0];
    const float* Y = (const float*)d_in[1];
    float* out = (float*)d_out;
    float* ws  = (float*)d_ws;   // 384 floats: [pair*128 + a]

    sig_pde_kernel<<<dim3(384), dim3(512), 0, stream>>>(X, Y, ws);
    sig_reduce_kernel<<<dim3(1), dim3(128), 0, stream>>>(ws, out);
}

// Round 2
// 212.484 us; speedup vs baseline: 1.5085x; 1.5085x over previous
//
#include <hip/hip_runtime.h>

#define D 16
#define MI 511                  // interior rows/cols of K grid
#define NSTEPS (64 + MI - 1)    // 574 pipeline steps
#define SY_STRIDE 18            // floats; 72B rows -> 4-way b64 aliasing only

// One wave (64 lanes) per (pair, batch) problem. Lane l owns K-rows
// [1+8l .. 8l+8]; walks columns 1..511 skewed by lane (c = s - l + 1).
// Bottom-row handoff via shfl_up; no __syncthreads in the main loop.
__global__ __launch_bounds__(64, 2)
void sig_pde_kernel(const float* __restrict__ X, const float* __restrict__ Y,
                    float* __restrict__ out) {
    __shared__ float sy[MI * SY_STRIDE];   // dY rows, ~36.8 KB

    const int idx  = blockIdx.x;
    const int pair = idx >> 7;             // 0: XX, 1: YY, 2: XY
    const int a    = idx & 127;
    const float* Pp = (pair == 1) ? Y : X;
    const float* Qp = (pair == 0) ? X : Y;
    const float* prow = Pp + (size_t)a * 512 * D;
    const float* qrow = Qp + (size_t)a * 512 * D;

    const int l = threadIdx.x;

    // Stage dY rows into LDS (one-time).
    for (int j = l; j < MI; j += 64) {
        const float4* r1 = (const float4*)(qrow + (size_t)(j + 1) * D);
        const float4* r0 = (const float4*)(qrow + (size_t)j * D);
        #pragma unroll
        for (int q = 0; q < 4; ++q) {
            float4 v1 = r1[q], v0 = r0[q];
            sy[j * SY_STRIDE + 4*q + 0] = v1.x - v0.x;
            sy[j * SY_STRIDE + 4*q + 1] = v1.y - v0.y;
            sy[j * SY_STRIDE + 4*q + 2] = v1.z - v0.z;
            sy[j * SY_STRIDE + 4*q + 3] = v1.w - v0.w;
        }
    }

    // dX rows for this lane's 8 K-rows into registers (128 VGPRs).
    // K-row g = 1+8l+r uses dX[g-1] = dX[8l+r]; clamp fake row (lane 63, r=7).
    float xr[8][D];
    #pragma unroll
    for (int r = 0; r < 8; ++r) {
        int gi = 8 * l + r;
        if (gi > MI - 1) gi = MI - 1;
        const float4* r1 = (const float4*)(prow + (size_t)(gi + 1) * D);
        const float4* r0 = (const float4*)(prow + (size_t)gi * D);
        #pragma unroll
        for (int q = 0; q < 4; ++q) {
            float4 v1 = r1[q], v0 = r0[q];
            xr[r][4*q + 0] = v1.x - v0.x;
            xr[r][4*q + 1] = v1.y - v0.y;
            xr[r][4*q + 2] = v1.z - v0.z;
            xr[r][4*q + 3] = v1.w - v0.w;
        }
    }
    __syncthreads();

    // K-state: kleft[r] = K[row_r][c-1]; col 0 boundary = 1.
    float kleft[8];
    #pragma unroll
    for (int r = 0; r < 8; ++r) kleft[r] = 1.0f;
    float bot = 1.0f;        // bottom-row value passed to lane l+1
    float ktop_prev = 1.0f;  // K[top-1][c-1] (diagonal from above)

    for (int s = 0; s < NSTEPS; ++s) {
        float ktop = __shfl_up(bot, 1, 64);   // K[top-1][c] from lane l-1
        if (l == 0) ktop = 1.0f;              // grid row 0 boundary
        const int c = s - l + 1;
        if (c >= 1 && c <= MI) {
            const float* yp = &sy[(size_t)(c - 1) * SY_STRIDE];
            float2 y2[8];
            #pragma unroll
            for (int q = 0; q < 8; ++q)
                y2[q] = *(const float2*)(yp + 2 * q);

            float know = ktop;       // K[i-1][c]
            float kd   = ktop_prev;  // K[i-1][c-1]
            #pragma unroll
            for (int r = 0; r < 8; ++r) {
                float2 acc = make_float2(-1.0f, 0.0f);  // fold the (inc-1)
                #pragma unroll
                for (int q = 0; q < 8; ++q) {
                    acc.x = fmaf(xr[r][2*q + 0], y2[q].x, acc.x);
                    acc.y = fmaf(xr[r][2*q + 1], y2[q].y, acc.y);
                }
                float dotm1 = acc.x + acc.y;
                float kl = kleft[r];                    // K[i][c-1]
                float v  = fmaf(kd, dotm1, know + kl);  // recurrence
                kd   = kl;                              // old K[i][c-1] -> next diag
                know = v;
                kleft[r] = v;
            }
            bot = kleft[7];
        }
        ktop_prev = ktop;
    }

    // K[511][511]: lane 63, local row r = 6.
    if (l == 63) out[idx] = kleft[6];
}

__global__ void sig_reduce_kernel(const float* __restrict__ ws,
                                  float* __restrict__ out) {
    const int a = threadIdx.x;  // 128 threads
    float v = ws[a] + ws[128 + a] - 2.0f * ws[256 + a];
    #pragma unroll
    for (int off = 32; off >= 1; off >>= 1) v += __shfl_down(v, off, 64);
    __shared__ float partial[2];
    if ((a & 63) == 0) partial[a >> 6] = v;
    __syncthreads();
    if (a == 0) out[0] = (partial[0] + partial[1]) * (1.0f / 128.0f);
}

extern "C" void kernel_launch(void* const* d_in, const int* in_sizes, int n_in,
                              void* d_out, int out_size, void* d_ws, size_t ws_size,
                              hipStream_t stream) {
    const float* X = (const float*)d_in[0];
    const float* Y = (const float*)d_in[1];
    float* out = (float*)d_out;
    float* ws  = (float*)d_ws;   // 384 floats: [pair*128 + a]

    sig_pde_kernel<<<dim3(384), dim3(64), 0, stream>>>(X, Y, ws);
    sig_reduce_kernel<<<dim3(1), dim3(128), 0, stream>>>(ws, out);
}

// Round 3
// 210.853 us; speedup vs baseline: 1.5202x; 1.0077x over previous
//
#include <hip/hip_runtime.h>

#define D 16
#define MI 511                  // interior rows/cols of K grid
#define NSTEPS (2 * 63 + MI)    // 637 pipeline steps (skew-2)
#define SY_STRIDE 18            // floats/row; keeps float2 loads 8B-aligned

typedef float v2f __attribute__((ext_vector_type(2)));

// One wave per (pair, batch) problem. Lane l owns K-rows [1+8l .. 8l+8];
// walks columns skewed 2 per lane (c = s - 2l + 1) so the shfl_up handoff
// has a full step of slack. y-rows double-buffered (prefetch c+1 while
// computing c). No barriers in the main loop.
__global__ __launch_bounds__(64, 1)
void sig_pde_kernel(const float* __restrict__ X, const float* __restrict__ Y,
                    float* __restrict__ out) {
    __shared__ float sy[MI * SY_STRIDE];   // dY rows, ~36.8 KB

    const int idx  = blockIdx.x;
    const int pair = idx >> 7;             // 0: XX, 1: YY, 2: XY
    const int a    = idx & 127;
    const float* Pp = (pair == 1) ? Y : X;
    const float* Qp = (pair == 0) ? X : Y;
    const float* prow = Pp + (size_t)a * 512 * D;
    const float* qrow = Qp + (size_t)a * 512 * D;

    const int l  = threadIdx.x;
    const int l2 = 2 * l;

    // Stage dY rows into LDS (one-time).
    for (int j = l; j < MI; j += 64) {
        const float4* r1 = (const float4*)(qrow + (size_t)(j + 1) * D);
        const float4* r0 = (const float4*)(qrow + (size_t)j * D);
        #pragma unroll
        for (int q = 0; q < 4; ++q) {
            float4 v1 = r1[q], v0 = r0[q];
            sy[j * SY_STRIDE + 4*q + 0] = v1.x - v0.x;
            sy[j * SY_STRIDE + 4*q + 1] = v1.y - v0.y;
            sy[j * SY_STRIDE + 4*q + 2] = v1.z - v0.z;
            sy[j * SY_STRIDE + 4*q + 3] = v1.w - v0.w;
        }
    }

    // dX rows for this lane's 8 K-rows, as float2 pairs (128 VGPRs).
    v2f xr[8][8];
    #pragma unroll
    for (int r = 0; r < 8; ++r) {
        int gi = 8 * l + r;
        if (gi > MI - 1) gi = MI - 1;          // lane 63 fake row
        const float4* r1 = (const float4*)(prow + (size_t)(gi + 1) * D);
        const float4* r0 = (const float4*)(prow + (size_t)gi * D);
        #pragma unroll
        for (int q = 0; q < 4; ++q) {
            float4 v1 = r1[q], v0 = r0[q];
            v2f t0; t0[0] = v1.x - v0.x; t0[1] = v1.y - v0.y;
            v2f t1; t1[0] = v1.z - v0.z; t1[1] = v1.w - v0.w;
            xr[r][2*q + 0] = t0;
            xr[r][2*q + 1] = t1;
        }
    }
    __syncthreads();

    float kleft[8];
    #pragma unroll
    for (int r = 0; r < 8; ++r) kleft[r] = 1.0f;
    float bot_prev     = 1.0f;  // this lane's bottom-row K at its last column
    float arrived      = 1.0f;  // K[top-1][c]   (shfl issued last step)
    float arrived_prev = 1.0f;  // K[top-1][c-1]

#define LOADY(CC, BUF) do {                                                  \
        int cc_ = (CC); cc_ = cc_ < 1 ? 1 : (cc_ > MI ? MI : cc_);           \
        const float* yp_ = &sy[(size_t)(cc_ - 1) * SY_STRIDE];               \
        _Pragma("unroll")                                                    \
        for (int q_ = 0; q_ < 8; ++q_) BUF[q_] = *(const v2f*)(yp_ + 2*q_);  \
    } while (0)

#define STEP(S, YC, YN) do {                                                 \
        float incoming_ = __shfl_up(bot_prev, 1, 64);                        \
        if (l == 0) incoming_ = 1.0f;      /* grid row 0 boundary */         \
        const int c_ = (S) - l2 + 1;                                         \
        LOADY(c_ + 1, YN);                 /* prefetch next column */        \
        if (c_ >= 1 && c_ <= MI) {                                           \
            float know_ = arrived;         /* K[i-1][c]   */                 \
            float kd_   = arrived_prev;    /* K[i-1][c-1] */                 \
            _Pragma("unroll")                                                \
            for (int r_ = 0; r_ < 8; ++r_) {                                 \
                v2f acc_; acc_[0] = -1.0f; acc_[1] = 0.0f;                   \
                _Pragma("unroll")                                            \
                for (int q_ = 0; q_ < 8; ++q_)                               \
                    acc_ = __builtin_elementwise_fma(xr[r_][q_], YC[q_], acc_); \
                float dotm1_ = acc_[0] + acc_[1];                            \
                float kl_ = kleft[r_];                                       \
                float v_  = fmaf(kd_, dotm1_, know_ + kl_);                  \
                kd_ = kl_; know_ = v_; kleft[r_] = v_;                       \
            }                                                                \
            bot_prev = kleft[7];                                             \
        }                                                                    \
        arrived_prev = arrived;                                              \
        arrived = incoming_;                                                 \
    } while (0)

    v2f yA[8], yB[8];
    LOADY(1 - l2, yA);                      // column for s = 0
    for (int s = 0; s < NSTEPS - 1; s += 2) {
        STEP(s,     yA, yB);
        STEP(s + 1, yB, yA);
    }
    STEP(NSTEPS - 1, yA, yB);               // s = 636 (even count: yA current)

#undef STEP
#undef LOADY

    // K[511][511]: lane 63, local row r = 6.
    if (l == 63) out[idx] = kleft[6];
}

__global__ void sig_reduce_kernel(const float* __restrict__ ws,
                                  float* __restrict__ out) {
    const int a = threadIdx.x;  // 128 threads
    float v = ws[a] + ws[128 + a] - 2.0f * ws[256 + a];
    #pragma unroll
    for (int off = 32; off >= 1; off >>= 1) v += __shfl_down(v, off, 64);
    __shared__ float partial[2];
    if ((a & 63) == 0) partial[a >> 6] = v;
    __syncthreads();
    if (a == 0) out[0] = (partial[0] + partial[1]) * (1.0f / 128.0f);
}

extern "C" void kernel_launch(void* const* d_in, const int* in_sizes, int n_in,
                              void* d_out, int out_size, void* d_ws, size_t ws_size,
                              hipStream_t stream) {
    const float* X = (const float*)d_in[0];
    const float* Y = (const float*)d_in[1];
    float* out = (float*)d_out;
    float* ws  = (float*)d_ws;   // 384 floats: [pair*128 + a]

    sig_pde_kernel<<<dim3(384), dim3(64), 0, stream>>>(X, Y, ws);
    sig_reduce_kernel<<<dim3(1), dim3(128), 0, stream>>>(ws, out);
}